// Round 6
// baseline (296.266 us; speedup 1.0000x reference)
//
#include <hip/hip_runtime.h>

// PositionId, position-major balanced scatter — identical to v5 except the
// output stores are PLAIN stores (single-variable A/B vs nontemporal).
// block b owns positions p_k = b + k*pstride; each buffer row is read from
// HBM exactly once (32 MB); writes (268 MB) are wave-coalesced 1KB chunks.
//
// buffer: [8192, 1024] fp32, offsets: [17] int32, out: [65536, 1024] fp32.

#define D_MODEL 1024
#define V4 (D_MODEL / 4)        // 256 float4 per row; one thread per float4 col
#define RPOS 8                  // positions per block, strided across the range
#define MAX_OFF 64              // generous bound for offsets in LDS

typedef float v4f __attribute__((ext_vector_type(4)));

__global__ __launch_bounds__(256, 8) void positionid_scatter(
    const v4f* __restrict__ buf,         // [buf_rows, 256] as v4f
    const int* __restrict__ offsets,     // [n_off]
    int n_off,                           // BATCH+1 (17)
    v4f*       __restrict__ out,         // [T, 256] as v4f
    int buf_rows,
    int pstride)                         // ceil(buf_rows / RPOS)
{
    __shared__ int soff[MAX_OFF];
    const int tid = threadIdx.x;
    if (tid < n_off) soff[tid] = offsets[tid];
    __syncthreads();

    const int b = blockIdx.x;            // b in [0, pstride)

    // Load this block's strided buffer rows once (RPOS independent loads in
    // flight). p_k = b + k*pstride; guard the tail.
    int  p[RPOS];
    v4f  v[RPOS];
    #pragma unroll
    for (int k = 0; k < RPOS; ++k) {
        p[k] = b + k * pstride;
        v[k] = buf[(size_t)(p[k] < buf_rows ? p[k] : 0) * V4 + tid];
    }

    // Broadcast each position to every segment containing it.
    // (p, len) are block-uniform -> scalar predicates, zero divergence.
    const int nseg = n_off - 1;
    for (int i = 0; i < nseg; ++i) {
        const int base = soff[i];
        const int len  = soff[i + 1] - base;   // len <= buf_rows
        #pragma unroll
        for (int k = 0; k < RPOS; ++k) {
            if (p[k] < len)                    // implies p[k] < buf_rows
                out[(size_t)(base + p[k]) * V4 + tid] = v[k];
        }
    }
}

extern "C" void kernel_launch(void* const* d_in, const int* in_sizes, int n_in,
                              void* d_out, int out_size, void* d_ws, size_t ws_size,
                              hipStream_t stream) {
    const v4f* buf     = (const v4f*)d_in[0];
    const int* offsets = (const int*)d_in[1];
    const int  n_off   = in_sizes[1];              // 17 (element count)
    v4f*       out     = (v4f*)d_out;

    const int buf_rows = in_sizes[0] / D_MODEL;    // 8192
    const int pstride  = (buf_rows + RPOS - 1) / RPOS;   // 1024

    positionid_scatter<<<dim3(pstride), dim3(256), 0, stream>>>(
        buf, offsets, n_off, out, buf_rows, pstride);
}

// Round 7
// 295.753 us; speedup vs baseline: 1.0017x; 1.0017x over previous
//
#include <hip/hip_runtime.h>

// DIAGNOSTIC ROUND: v5/v6 balanced position-major scatter with the grid cut
// to 128 blocks so the dispatch runs long enough (>200us) to appear in the
// rocprof top-5 WITH its FETCH_SIZE/WRITE_SIZE counters. Memory traffic is
// identical to v6 (32 MB reads, 268 MB writes); only TLP changes.
// Purpose: determine whether our output stores read-allocate in L2
// (FETCH ~300 MB) or not (FETCH ~33 MB). The fill kernel shows FETCH~0 while
// writing 1 GiB, so no-allocate streaming writes are achievable on this HW.
//
// buffer: [8192, 1024] fp32, offsets: [17] int32, out: [65536, 1024] fp32.

#define D_MODEL 1024
#define V4 (D_MODEL / 4)   // 256 float4 per row; one thread per float4 col
#define NBLK 128           // blocks; position stride
#define CH 8               // positions per inner chunk (8 loads in flight)
#define MAX_OFF 64

typedef float v4f __attribute__((ext_vector_type(4)));

__global__ __launch_bounds__(256) void positionid_scatter_diag(
    const v4f* __restrict__ buf,         // [buf_rows, 256] as v4f
    const int* __restrict__ offsets,     // [n_off]
    int n_off,                           // BATCH+1 (17)
    v4f*       __restrict__ out,         // [T, 256] as v4f
    int buf_rows)
{
    __shared__ int soff[MAX_OFF];
    const int tid = threadIdx.x;
    if (tid < n_off) soff[tid] = offsets[tid];
    __syncthreads();

    const int b = blockIdx.x;            // 0..NBLK-1
    const int nseg = n_off - 1;
    const int mmax = (buf_rows + NBLK - 1) / NBLK;   // 64 positions per block

    for (int m0 = 0; m0 < mmax; m0 += CH) {
        int p[CH];
        v4f v[CH];
        #pragma unroll
        for (int k = 0; k < CH; ++k) {
            p[k] = b + (m0 + k) * NBLK;
            v[k] = buf[(size_t)(p[k] < buf_rows ? p[k] : 0) * V4 + tid];
        }
        for (int i = 0; i < nseg; ++i) {
            const int base = soff[i];
            const int len  = soff[i + 1] - base;   // len <= buf_rows
            #pragma unroll
            for (int k = 0; k < CH; ++k) {
                if (p[k] < len)                    // implies p[k] < buf_rows
                    out[(size_t)(base + p[k]) * V4 + tid] = v[k];
            }
        }
    }
}

extern "C" void kernel_launch(void* const* d_in, const int* in_sizes, int n_in,
                              void* d_out, int out_size, void* d_ws, size_t ws_size,
                              hipStream_t stream) {
    const v4f* buf     = (const v4f*)d_in[0];
    const int* offsets = (const int*)d_in[1];
    const int  n_off   = in_sizes[1];              // 17 (element count)
    v4f*       out     = (v4f*)d_out;

    const int buf_rows = in_sizes[0] / D_MODEL;    // 8192

    positionid_scatter_diag<<<dim3(NBLK), dim3(256), 0, stream>>>(
        buf, offsets, n_off, out, buf_rows);
}